// Round 11
// baseline (85.799 us; speedup 1.0000x reference)
//
#include <hip/hip_runtime.h>

#define B 8
#define C 512
#define D 2048     // spatial positions
#define L 2049     // D+1
#define NH 8
#define CH 64
#define NCQ 4      // c-quarter splits in k_logits

__device__ __forceinline__ float wave_sum(float v) {
  #pragma unroll
  for (int off = 32; off; off >>= 1) v += __shfl_down(v, off);
  return v;
}
__device__ __forceinline__ float wave_max(float v) {
  #pragma unroll
  for (int off = 32; off; off >>= 1) v = fmaxf(v, __shfl_down(v, off));
  return v;
}
__device__ __forceinline__ float lane_bcast(float v, int l) {
  return __uint_as_float(__builtin_amdgcn_readlane(__float_as_uint(v), l));
}

// ---- K1: mps[b,c] = mean_l x[b,c,l] + pos[c,0]. One block per (b,c) row. ----
__global__ void __launch_bounds__(256) k_mean(const float* __restrict__ x,
                                              const float* __restrict__ pos,
                                              float* __restrict__ mps_g) {
  int row = blockIdx.x;  // b*C + c
  const float4* xr = reinterpret_cast<const float4*>(x + (size_t)row * D);
  float s = 0.f;
  #pragma unroll
  for (int i = 0; i < 2; ++i) {
    float4 v = xr[threadIdx.x + i * 256];
    s += (v.x + v.y) + (v.z + v.w);
  }
  __shared__ float red[4];
  s = wave_sum(s);
  if ((threadIdx.x & 63) == 0) red[threadIdx.x >> 6] = s;
  __syncthreads();
  if (threadIdx.x == 0)
    mps_g[row] = (red[0] + red[1] + red[2] + red[3]) * (1.0f / D)
               + pos[(size_t)(row & (C - 1)) * L];
}

// ---- K2: q0 -> u[b,h,:] -> logit0[b,h]. One block per (b,h). ----
__global__ void __launch_bounds__(256) k_qu(const float* __restrict__ wqkv,
                                            const float* __restrict__ bqkv,
                                            const float* __restrict__ mps_g,
                                            float* __restrict__ u,
                                            float* __restrict__ logit0) {
  int bh = blockIdx.x, b = bh >> 3, h = bh & 7;
  int tid = threadIdx.x, wid = tid >> 6, lane = tid & 63;
  __shared__ float mps[C];
  __shared__ float q0s[CH];
  __shared__ float us[C];
  __shared__ float red[4];
  for (int c = tid; c < C; c += 256) mps[c] = mps_g[b * C + c];
  __syncthreads();
  for (int j = wid; j < CH; j += 4) {
    const float* wr = wqkv + (size_t)(h * CH + j) * C;
    float acc = 0.f;
    #pragma unroll
    for (int k = 0; k < 8; ++k) acc += wr[lane + k * 64] * mps[lane + k * 64];
    acc = wave_sum(acc);
    if (lane == 0) q0s[j] = acc + bqkv[h * CH + j];
  }
  __syncthreads();
  float a0 = 0.f, a1 = 0.f;
  #pragma unroll 4
  for (int j = 0; j < CH; ++j) {
    float qv = q0s[j];
    const float* wkr = wqkv + (size_t)(C + h * CH + j) * C;
    a0 += qv * wkr[tid];
    a1 += qv * wkr[tid + 256];
  }
  a0 *= 0.125f; a1 *= 0.125f;   // scale^2 = 1/sqrt(64)
  us[tid] = a0; us[tid + 256] = a1;
  u[(size_t)bh * C + tid] = a0;
  u[(size_t)bh * C + tid + 256] = a1;
  __syncthreads();
  float p = us[tid] * mps[tid] + us[tid + 256] * mps[tid + 256];
  p = wave_sum(p);
  if (lane == 0) red[wid] = p;
  __syncthreads();
  if (tid == 0) logit0[bh] = red[0] + red[1] + red[2] + red[3];
}

// ---- K3: logit partials. grid (8 lt, B, 4 cq) = 256 blocks, 512 thr.
// Wave w owns 16 c-rows; lane owns 4 l (float4 -> 1 KB contiguous per row
// per wave-instruction). u broadcast from LDS (same-address read = free).
// 8-wave reduce in LDS. wpart[(bh*4+cq)][j] = sum_{c in q} u[bh,c]*xf[c,j+1]. ----
__global__ void __launch_bounds__(512) k_logits(
    const float* __restrict__ x, const float* __restrict__ pos,
    const float* __restrict__ u_g, float* __restrict__ wpart) {
  __shared__ float us[NH][128];
  __shared__ float4 rlds[8][NH][64];   // 64 KB
  int lt = blockIdx.x, b = blockIdx.y, cq = blockIdx.z;
  int tid = threadIdx.x, w = tid >> 6, lane = tid & 63;
  for (int idx = tid; idx < NH * 128; idx += 512) {
    int h = idx >> 7, cc = idx & 127;
    us[h][cc] = u_g[(size_t)(b * NH + h) * C + cq * 128 + cc];
  }
  __syncthreads();
  float4 acc[NH];
  #pragma unroll
  for (int h = 0; h < NH; ++h) acc[h] = make_float4(0.f, 0.f, 0.f, 0.f);
  int c0 = cq * 128 + w * 16;
  int jb = lt * 256 + lane * 4;        // x column base for this lane
  const float4* x4 = reinterpret_cast<const float4*>(x)
                   + ((size_t)(b * C + c0)) * (D / 4) + (jb >> 2);
  const float* pb = pos + (size_t)c0 * L + jb + 1;
  #pragma unroll
  for (int r = 0; r < 16; ++r) {
    float4 v = x4[(size_t)r * (D / 4)];
    const float* pr = pb + (size_t)r * L;
    v.x += pr[0]; v.y += pr[1]; v.z += pr[2]; v.w += pr[3];
    #pragma unroll
    for (int h = 0; h < NH; ++h) {
      float uu = us[h][w * 16 + r];    // block-uniform broadcast
      acc[h].x += uu * v.x; acc[h].y += uu * v.y;
      acc[h].z += uu * v.z; acc[h].w += uu * v.w;
    }
  }
  #pragma unroll
  for (int h = 0; h < NH; ++h) rlds[w][h][lane] = acc[h];
  __syncthreads();
  int h = tid >> 6, slot = tid & 63;   // 512 threads <-> (h, slot)
  float4 s = rlds[0][h][slot];
  #pragma unroll
  for (int w2 = 1; w2 < 8; ++w2) {
    float4 t = rlds[w2][h][slot];
    s.x += t.x; s.y += t.y; s.z += t.z; s.w += t.w;
  }
  reinterpret_cast<float4*>(
      wpart + ((size_t)((b * NH + h) * NCQ + cq)) * (size_t)D + lt * 256)[slot] = s;
}

// ---- K4: xbar. grid (32 cc, B) = 256 blocks, 512 thr.
// Step 1 (redundant per block): combine 4 c-partials -> softmax e[8][2048] in
// LDS (+ e0, sinv). Step 2: stream 16 xf rows (x float4 + pos scalar adds),
// dot against e -> xbar[b,h,c] normalized incl. l=0 term. ----
__global__ void __launch_bounds__(512) k_xbar(
    const float* __restrict__ x, const float* __restrict__ pos,
    const float* __restrict__ wpart, const float* __restrict__ logit0,
    const float* __restrict__ mps_g, float* __restrict__ xbar) {
  __shared__ float eL[NH][D];          // 64 KB
  __shared__ float sinv[NH], w0e[NH];
  int cc = blockIdx.x, b = blockIdx.y;
  int tid = threadIdx.x, w = tid >> 6, lane = tid & 63;
  {
    int h = w, bh = b * NH + h;
    const float* wp = wpart + (size_t)(bh * NCQ) * D;
    float s_arr[32];
    float m = -3.0e38f;
    #pragma unroll
    for (int k = 0; k < 32; ++k) {
      int l = k * 64 + lane;
      float s = wp[l] + wp[D + l] + wp[2 * D + l] + wp[3 * D + l];
      s_arr[k] = s;
      m = fmaxf(m, s);
    }
    float lg0 = logit0[bh];
    float M = fmaxf(lane_bcast(wave_max(m), 0), lg0);
    float ssum = 0.f;
    #pragma unroll
    for (int k = 0; k < 32; ++k) {
      float e = __expf(s_arr[k] - M);
      eL[h][k * 64 + lane] = e;
      ssum += e;
    }
    float e0 = __expf(lg0 - M);
    float S = lane_bcast(wave_sum(ssum), 0) + e0;
    if (lane == 0) { sinv[h] = 1.0f / S; w0e[h] = e0; }
  }
  __syncthreads();
  int c0 = cc * 16 + w * 2;            // wave owns 2 c-rows
  float accr[2][NH];
  #pragma unroll
  for (int r = 0; r < 2; ++r)
    #pragma unroll
    for (int h = 0; h < NH; ++h) accr[r][h] = 0.f;
  const float4* x4 = reinterpret_cast<const float4*>(x) + ((size_t)(b * C + c0)) * (D / 4);
  const float* pb = pos + (size_t)c0 * L + 1;   // pos[c0][l], l = j+1
  #pragma unroll
  for (int k = 0; k < 8; ++k) {
    int fi = k * 64 + lane;            // float4 index in row
    float4 e4[NH];
    #pragma unroll
    for (int h = 0; h < NH; ++h)
      e4[h] = reinterpret_cast<const float4*>(eL[h])[fi];
    #pragma unroll
    for (int r = 0; r < 2; ++r) {
      float4 xv = x4[(size_t)r * (D / 4) + fi];
      const float* pr = pb + (size_t)r * L + fi * 4;  // pos[c0+r][j+1..j+4]
      xv.x += pr[0]; xv.y += pr[1]; xv.z += pr[2]; xv.w += pr[3];
      #pragma unroll
      for (int h = 0; h < NH; ++h)
        accr[r][h] += e4[h].x * xv.x + e4[h].y * xv.y
                    + e4[h].z * xv.z + e4[h].w * xv.w;
    }
  }
  #pragma unroll
  for (int r = 0; r < 2; ++r) {
    int c = c0 + r;
    float mv = mps_g[b * C + c];
    #pragma unroll
    for (int h = 0; h < NH; ++h) {
      float t = wave_sum(accr[r][h]);
      if (lane == 0)
        xbar[(size_t)(b * NH + h) * C + c] = (t + w0e[h] * mv) * sinv[h];
    }
  }
}

// ---- K5: a0[b, h*64+j] = W_v[o,:].xbar[b,h,:] + b_v[o]. Block = (b,h). ----
__global__ void __launch_bounds__(512) k_a0(
    const float* __restrict__ xbarg, const float* __restrict__ wqkv,
    const float* __restrict__ bqkv, float* __restrict__ a0v) {
  int bh = blockIdx.x, b = bh >> 3, h = bh & 7;
  int tid = threadIdx.x, wid = tid >> 6, lane = tid & 63;
  __shared__ float row[C];
  row[tid] = xbarg[(size_t)bh * C + tid];
  __syncthreads();
  float xr[8];
  #pragma unroll
  for (int k = 0; k < 8; ++k) xr[k] = row[k * 64 + lane];
  #pragma unroll 2
  for (int j = 0; j < 8; ++j) {
    int o = h * CH + wid * 8 + j;
    const float* wr = wqkv + (size_t)(2 * C + o) * C;
    float d = 0.f;
    #pragma unroll
    for (int k = 0; k < 8; ++k) d += wr[k * 64 + lane] * xr[k];
    d = wave_sum(d);
    if (lane == 0) a0v[b * C + o] = d + bqkv[2 * C + o];
  }
}

// ---- K6: out[b,o] = W_c[o,:].a0[b,:] + b_c[o]. Block = (b, 64-o chunk). ----
__global__ void __launch_bounds__(512) k_out(const float* __restrict__ wc,
                                             const float* __restrict__ bc,
                                             const float* __restrict__ a0v,
                                             float* __restrict__ out) {
  int bid = blockIdx.x, b = bid >> 3, og = (bid & 7) * 64;
  int tid = threadIdx.x, wid = tid >> 6, lane = tid & 63;
  __shared__ float row[C];
  row[tid] = a0v[b * C + tid];
  __syncthreads();
  float ar[8];
  #pragma unroll
  for (int k = 0; k < 8; ++k) ar[k] = row[k * 64 + lane];
  #pragma unroll 2
  for (int j = 0; j < 8; ++j) {
    int o = og + wid * 8 + j;
    const float* wr = wc + (size_t)o * C;
    float d = 0.f;
    #pragma unroll
    for (int k = 0; k < 8; ++k) d += wr[k * 64 + lane] * ar[k];
    d = wave_sum(d);
    if (lane == 0) out[b * C + o] = d + bc[o];
  }
}

extern "C" void kernel_launch(void* const* d_in, const int* in_sizes, int n_in,
                              void* d_out, int out_size, void* d_ws, size_t ws_size,
                              hipStream_t stream) {
  const float* x    = (const float*)d_in[0];
  const float* pos  = (const float*)d_in[1];
  const float* wqkv = (const float*)d_in[2];
  const float* bqkv = (const float*)d_in[3];
  const float* wc   = (const float*)d_in[4];
  const float* bc   = (const float*)d_in[5];
  float* out = (float*)d_out;
  float* ws  = (float*)d_ws;

  float* mps_g  = ws;               // 4096
  float* u      = ws + 4096;        // 32768
  float* logit0 = ws + 36864;       // 64
  float* a0v    = ws + 36928;       // 4096
  float* xbarg  = ws + 41024;       // 32768
  float* wpart  = ws + 73792;       // 64*4*2048 = 524288  (total ~2.4 MB)

  hipLaunchKernelGGL(k_mean,   dim3(B * C),       dim3(256), 0, stream, x, pos, mps_g);
  hipLaunchKernelGGL(k_qu,     dim3(B * NH),      dim3(256), 0, stream, wqkv, bqkv, mps_g, u, logit0);
  hipLaunchKernelGGL(k_logits, dim3(8, B, NCQ),   dim3(512), 0, stream, x, pos, u, wpart);
  hipLaunchKernelGGL(k_xbar,   dim3(32, B),       dim3(512), 0, stream, x, pos, wpart, logit0, mps_g, xbarg);
  hipLaunchKernelGGL(k_a0,     dim3(B * NH),      dim3(512), 0, stream, xbarg, wqkv, bqkv, a0v);
  hipLaunchKernelGGL(k_out,    dim3(B * NH),      dim3(512), 0, stream, wc, bc, a0v, out);
}

// Round 12
// 85.257 us; speedup vs baseline: 1.0064x; 1.0064x over previous
//
#include <hip/hip_runtime.h>

#define B 8
#define C 512
#define D 2048     // spatial positions
#define L 2049     // D+1
#define NH 8
#define CH 64
#define NCQ 4      // c-quarter splits in k_logits

__device__ __forceinline__ float wave_sum(float v) {
  #pragma unroll
  for (int off = 32; off; off >>= 1) v += __shfl_down(v, off);
  return v;
}
__device__ __forceinline__ float wave_max(float v) {
  #pragma unroll
  for (int off = 32; off; off >>= 1) v = fmaxf(v, __shfl_down(v, off));
  return v;
}
__device__ __forceinline__ float lane_bcast(float v, int l) {
  return __uint_as_float(__builtin_amdgcn_readlane(__float_as_uint(v), l));
}

// ---- K1: mps[b,c] = mean_l x[b,c,l] + pos[c,0]. One block per (b,c) row. ----
__global__ void __launch_bounds__(256) k_mean(const float* __restrict__ x,
                                              const float* __restrict__ pos,
                                              float* __restrict__ mps_g) {
  int row = blockIdx.x;  // b*C + c
  const float4* xr = reinterpret_cast<const float4*>(x + (size_t)row * D);
  float s = 0.f;
  #pragma unroll
  for (int i = 0; i < 2; ++i) {
    float4 v = xr[threadIdx.x + i * 256];
    s += (v.x + v.y) + (v.z + v.w);
  }
  __shared__ float red[4];
  s = wave_sum(s);
  if ((threadIdx.x & 63) == 0) red[threadIdx.x >> 6] = s;
  __syncthreads();
  if (threadIdx.x == 0)
    mps_g[row] = (red[0] + red[1] + red[2] + red[3]) * (1.0f / D)
               + pos[(size_t)(row & (C - 1)) * L];
}

// ---- K2: q0 -> u[b,h,:] -> logit0[b,h]. One block per (b,h). ----
__global__ void __launch_bounds__(256) k_qu(const float* __restrict__ wqkv,
                                            const float* __restrict__ bqkv,
                                            const float* __restrict__ mps_g,
                                            float* __restrict__ u,
                                            float* __restrict__ logit0) {
  int bh = blockIdx.x, b = bh >> 3, h = bh & 7;
  int tid = threadIdx.x, wid = tid >> 6, lane = tid & 63;
  __shared__ float mps[C];
  __shared__ float q0s[CH];
  __shared__ float us[C];
  __shared__ float red[4];
  for (int c = tid; c < C; c += 256) mps[c] = mps_g[b * C + c];
  __syncthreads();
  for (int j = wid; j < CH; j += 4) {
    const float* wr = wqkv + (size_t)(h * CH + j) * C;
    float acc = 0.f;
    #pragma unroll
    for (int k = 0; k < 8; ++k) acc += wr[lane + k * 64] * mps[lane + k * 64];
    acc = wave_sum(acc);
    if (lane == 0) q0s[j] = acc + bqkv[h * CH + j];
  }
  __syncthreads();
  float a0 = 0.f, a1 = 0.f;
  #pragma unroll 4
  for (int j = 0; j < CH; ++j) {
    float qv = q0s[j];
    const float* wkr = wqkv + (size_t)(C + h * CH + j) * C;
    a0 += qv * wkr[tid];
    a1 += qv * wkr[tid + 256];
  }
  a0 *= 0.125f; a1 *= 0.125f;   // scale^2 = 1/sqrt(64)
  us[tid] = a0; us[tid + 256] = a1;
  u[(size_t)bh * C + tid] = a0;
  u[(size_t)bh * C + tid + 256] = a1;
  __syncthreads();
  float p = us[tid] * mps[tid] + us[tid + 256] * mps[tid + 256];
  p = wave_sum(p);
  if (lane == 0) red[wid] = p;
  __syncthreads();
  if (tid == 0) logit0[bh] = red[0] + red[1] + red[2] + red[3];
}

// ---- K3: logit partials. grid (8 lt, B, 4 cq) = 256 blocks, 512 thr. ----
__global__ void __launch_bounds__(512) k_logits(
    const float* __restrict__ x, const float* __restrict__ pos,
    const float* __restrict__ u_g, float* __restrict__ wpart) {
  __shared__ float us[NH][128];
  __shared__ float4 rlds[8][NH][64];   // 64 KB
  int lt = blockIdx.x, b = blockIdx.y, cq = blockIdx.z;
  int tid = threadIdx.x, w = tid >> 6, lane = tid & 63;
  for (int idx = tid; idx < NH * 128; idx += 512) {
    int h = idx >> 7, cc = idx & 127;
    us[h][cc] = u_g[(size_t)(b * NH + h) * C + cq * 128 + cc];
  }
  __syncthreads();
  float4 acc[NH];
  #pragma unroll
  for (int h = 0; h < NH; ++h) acc[h] = make_float4(0.f, 0.f, 0.f, 0.f);
  int c0 = cq * 128 + w * 16;
  int jb = lt * 256 + lane * 4;        // x column base for this lane
  const float4* x4 = reinterpret_cast<const float4*>(x)
                   + ((size_t)(b * C + c0)) * (D / 4) + (jb >> 2);
  const float* pb = pos + (size_t)c0 * L + jb + 1;
  #pragma unroll
  for (int r = 0; r < 16; ++r) {
    float4 v = x4[(size_t)r * (D / 4)];
    const float* pr = pb + (size_t)r * L;
    v.x += pr[0]; v.y += pr[1]; v.z += pr[2]; v.w += pr[3];
    #pragma unroll
    for (int h = 0; h < NH; ++h) {
      float uu = us[h][w * 16 + r];    // block-uniform broadcast
      acc[h].x += uu * v.x; acc[h].y += uu * v.y;
      acc[h].z += uu * v.z; acc[h].w += uu * v.w;
    }
  }
  #pragma unroll
  for (int h = 0; h < NH; ++h) rlds[w][h][lane] = acc[h];
  __syncthreads();
  int h = tid >> 6, slot = tid & 63;   // 512 threads <-> (h, slot)
  float4 s = rlds[0][h][slot];
  #pragma unroll
  for (int w2 = 1; w2 < 8; ++w2) {
    float4 t = rlds[w2][h][slot];
    s.x += t.x; s.y += t.y; s.z += t.z; s.w += t.w;
  }
  reinterpret_cast<float4*>(
      wpart + ((size_t)((b * NH + h) * NCQ + cq)) * (size_t)D + lt * 256)[slot] = s;
}

// ---- K4: softmax combine. One block per (b,h), 512 thr.
// Combine 4 c-quarter partials, softmax over 2049, write NORMALIZED weights
// e_g[bh][l] (sinv folded) and w0n[bh] = e0*sinv. ----
__global__ void __launch_bounds__(512) k_softmax(
    const float* __restrict__ wpart, const float* __restrict__ logit0,
    float* __restrict__ e_g, float* __restrict__ w0n) {
  int bh = blockIdx.x;
  int tid = threadIdx.x, wid = tid >> 6, lane = tid & 63;
  __shared__ float red[8];
  __shared__ float bc;
  const float* wp = wpart + (size_t)(bh * NCQ) * D;
  float s_arr[4];
  float m = -3.0e38f;
  #pragma unroll
  for (int k = 0; k < 4; ++k) {
    int l = k * 512 + tid;
    float s = wp[l] + wp[D + l] + wp[2 * D + l] + wp[3 * D + l];
    s_arr[k] = s;
    m = fmaxf(m, s);
  }
  float lg0 = logit0[bh];
  m = wave_max(m);
  if (lane == 0) red[wid] = m;
  __syncthreads();
  if (tid == 0) {
    float M = lg0;
    #pragma unroll
    for (int w = 0; w < 8; ++w) M = fmaxf(M, red[w]);
    bc = M;
  }
  __syncthreads();
  float M = bc;
  float e[4], ssum = 0.f;
  #pragma unroll
  for (int k = 0; k < 4; ++k) { e[k] = __expf(s_arr[k] - M); ssum += e[k]; }
  ssum = wave_sum(ssum);
  __syncthreads();
  if (lane == 0) red[wid] = ssum;
  __syncthreads();
  if (tid == 0) {
    float S = __expf(lg0 - M);
    #pragma unroll
    for (int w = 0; w < 8; ++w) S += red[w];
    bc = 1.0f / S;
  }
  __syncthreads();
  float sinv = bc;
  #pragma unroll
  for (int k = 0; k < 4; ++k)
    e_g[(size_t)bh * D + k * 512 + tid] = e[k] * sinv;
  if (tid == 0) w0n[bh] = __expf(lg0 - M) * sinv;
}

// ---- K5: xbar. grid (32 cc, B) = 256 blocks, 512 thr.
// Load b's normalized e (64 KB, float4, L2-shared by 32 blocks) into LDS,
// stream 16 xf rows (x float4 + coalesced pos scalars), dot -> xbar. ----
__global__ void __launch_bounds__(512) k_xbar(
    const float* __restrict__ x, const float* __restrict__ pos,
    const float* __restrict__ e_g, const float* __restrict__ w0n,
    const float* __restrict__ mps_g, float* __restrict__ xbar) {
  __shared__ float eL[NH][D];          // 64 KB
  int cc = blockIdx.x, b = blockIdx.y;
  int tid = threadIdx.x, w = tid >> 6, lane = tid & 63;
  {
    const float4* src = reinterpret_cast<const float4*>(e_g + (size_t)(b * NH) * D);
    float4* dst = reinterpret_cast<float4*>(&eL[0][0]);
    #pragma unroll
    for (int k = 0; k < 8; ++k) dst[k * 512 + tid] = src[k * 512 + tid];
  }
  __syncthreads();
  int c0 = cc * 16 + w * 2;            // wave owns 2 c-rows
  float accr[2][NH];
  #pragma unroll
  for (int r = 0; r < 2; ++r)
    #pragma unroll
    for (int h = 0; h < NH; ++h) accr[r][h] = 0.f;
  const float4* x4 = reinterpret_cast<const float4*>(x) + ((size_t)(b * C + c0)) * (D / 4);
  const float* pb = pos + (size_t)c0 * L + 1;   // pos[c0][l], l = j+1
  #pragma unroll
  for (int k = 0; k < 8; ++k) {
    int fi = k * 64 + lane;            // float4 index in row
    float4 e4[NH];
    #pragma unroll
    for (int h = 0; h < NH; ++h)
      e4[h] = reinterpret_cast<const float4*>(eL[h])[fi];
    #pragma unroll
    for (int r = 0; r < 2; ++r) {
      float4 xv = x4[(size_t)r * (D / 4) + fi];
      const float* pr = pb + (size_t)r * L + fi * 4;  // pos[c0+r][j+1..j+4]
      xv.x += pr[0]; xv.y += pr[1]; xv.z += pr[2]; xv.w += pr[3];
      #pragma unroll
      for (int h = 0; h < NH; ++h)
        accr[r][h] += e4[h].x * xv.x + e4[h].y * xv.y
                    + e4[h].z * xv.z + e4[h].w * xv.w;
    }
  }
  #pragma unroll
  for (int r = 0; r < 2; ++r) {
    int c = c0 + r;
    float mv = mps_g[b * C + c];
    #pragma unroll
    for (int h = 0; h < NH; ++h) {
      float t = wave_sum(accr[r][h]);
      if (lane == 0)
        xbar[(size_t)(b * NH + h) * C + c] = t + w0n[b * NH + h] * mv;
    }
  }
}

// ---- K6: a0[b, h*64+j] = W_v[o,:].xbar[b,h,:] + b_v[o]. Block = (b,h). ----
__global__ void __launch_bounds__(512) k_a0(
    const float* __restrict__ xbarg, const float* __restrict__ wqkv,
    const float* __restrict__ bqkv, float* __restrict__ a0v) {
  int bh = blockIdx.x, b = bh >> 3, h = bh & 7;
  int tid = threadIdx.x, wid = tid >> 6, lane = tid & 63;
  __shared__ float row[C];
  row[tid] = xbarg[(size_t)bh * C + tid];
  __syncthreads();
  float xr[8];
  #pragma unroll
  for (int k = 0; k < 8; ++k) xr[k] = row[k * 64 + lane];
  #pragma unroll 2
  for (int j = 0; j < 8; ++j) {
    int o = h * CH + wid * 8 + j;
    const float* wr = wqkv + (size_t)(2 * C + o) * C;
    float d = 0.f;
    #pragma unroll
    for (int k = 0; k < 8; ++k) d += wr[k * 64 + lane] * xr[k];
    d = wave_sum(d);
    if (lane == 0) a0v[b * C + o] = d + bqkv[2 * C + o];
  }
}

// ---- K7: out[b,o] = W_c[o,:].a0[b,:] + b_c[o]. Block = (b, 64-o chunk). ----
__global__ void __launch_bounds__(512) k_out(const float* __restrict__ wc,
                                             const float* __restrict__ bc,
                                             const float* __restrict__ a0v,
                                             float* __restrict__ out) {
  int bid = blockIdx.x, b = bid >> 3, og = (bid & 7) * 64;
  int tid = threadIdx.x, wid = tid >> 6, lane = tid & 63;
  __shared__ float row[C];
  row[tid] = a0v[b * C + tid];
  __syncthreads();
  float ar[8];
  #pragma unroll
  for (int k = 0; k < 8; ++k) ar[k] = row[k * 64 + lane];
  #pragma unroll 2
  for (int j = 0; j < 8; ++j) {
    int o = og + wid * 8 + j;
    const float* wr = wc + (size_t)o * C;
    float d = 0.f;
    #pragma unroll
    for (int k = 0; k < 8; ++k) d += wr[k * 64 + lane] * ar[k];
    d = wave_sum(d);
    if (lane == 0) out[b * C + o] = d + bc[o];
  }
}

extern "C" void kernel_launch(void* const* d_in, const int* in_sizes, int n_in,
                              void* d_out, int out_size, void* d_ws, size_t ws_size,
                              hipStream_t stream) {
  const float* x    = (const float*)d_in[0];
  const float* pos  = (const float*)d_in[1];
  const float* wqkv = (const float*)d_in[2];
  const float* bqkv = (const float*)d_in[3];
  const float* wc   = (const float*)d_in[4];
  const float* bc   = (const float*)d_in[5];
  float* out = (float*)d_out;
  float* ws  = (float*)d_ws;

  float* mps_g  = ws;               // 4096
  float* u      = ws + 4096;        // 32768
  float* logit0 = ws + 36864;       // 64
  float* a0v    = ws + 36928;       // 4096
  float* xbarg  = ws + 41024;       // 32768
  float* w0n    = ws + 73792;       // 64
  float* e_g    = ws + 73856;       // 64*2048 = 131072
  float* wpart  = ws + 204928;      // 64*4*2048 = 524288  (total ~2.9 MB)

  hipLaunchKernelGGL(k_mean,    dim3(B * C),     dim3(256), 0, stream, x, pos, mps_g);
  hipLaunchKernelGGL(k_qu,      dim3(B * NH),    dim3(256), 0, stream, wqkv, bqkv, mps_g, u, logit0);
  hipLaunchKernelGGL(k_logits,  dim3(8, B, NCQ), dim3(512), 0, stream, x, pos, u, wpart);
  hipLaunchKernelGGL(k_softmax, dim3(B * NH),    dim3(512), 0, stream, wpart, logit0, e_g, w0n);
  hipLaunchKernelGGL(k_xbar,    dim3(32, B),     dim3(512), 0, stream, x, pos, e_g, w0n, mps_g, xbarg);
  hipLaunchKernelGGL(k_a0,      dim3(B * NH),    dim3(512), 0, stream, xbarg, wqkv, bqkv, a0v);
  hipLaunchKernelGGL(k_out,     dim3(B * NH),    dim3(512), 0, stream, wc, bc, a0v, out);
}

// Round 13
// 61.757 us; speedup vs baseline: 1.3893x; 1.3805x over previous
//
#include <hip/hip_runtime.h>

#define B 8
#define C 512
#define D 2048     // spatial positions
#define L 2049     // D+1
#define NH 8
#define CH 64
#define NCQ 4      // c-quarter splits in k_logits

__device__ __forceinline__ float wave_sum(float v) {
  #pragma unroll
  for (int off = 32; off; off >>= 1) v += __shfl_down(v, off);
  return v;
}
__device__ __forceinline__ float wave_max(float v) {
  #pragma unroll
  for (int off = 32; off; off >>= 1) v = fmaxf(v, __shfl_down(v, off));
  return v;
}
__device__ __forceinline__ float lane_bcast(float v, int l) {
  return __uint_as_float(__builtin_amdgcn_readlane(__float_as_uint(v), l));
}

// ---- K1: mps[b,c] = mean_l x[b,c,l] + pos[c,0]. One block per (b,c) row. ----
__global__ void __launch_bounds__(256) k_mean(const float* __restrict__ x,
                                              const float* __restrict__ pos,
                                              float* __restrict__ mps_g) {
  int row = blockIdx.x;  // b*C + c
  const float4* xr = reinterpret_cast<const float4*>(x + (size_t)row * D);
  float s = 0.f;
  #pragma unroll
  for (int i = 0; i < 2; ++i) {
    float4 v = xr[threadIdx.x + i * 256];
    s += (v.x + v.y) + (v.z + v.w);
  }
  __shared__ float red[4];
  s = wave_sum(s);
  if ((threadIdx.x & 63) == 0) red[threadIdx.x >> 6] = s;
  __syncthreads();
  if (threadIdx.x == 0)
    mps_g[row] = (red[0] + red[1] + red[2] + red[3]) * (1.0f / D)
               + pos[(size_t)(row & (C - 1)) * L];
}

// ---- K2: q0 -> u[b,h,:] -> logit0[b,h]. One block per (b,h). ----
__global__ void __launch_bounds__(256) k_qu(const float* __restrict__ wqkv,
                                            const float* __restrict__ bqkv,
                                            const float* __restrict__ mps_g,
                                            float* __restrict__ u,
                                            float* __restrict__ logit0) {
  int bh = blockIdx.x, b = bh >> 3, h = bh & 7;
  int tid = threadIdx.x, wid = tid >> 6, lane = tid & 63;
  __shared__ float mps[C];
  __shared__ float q0s[CH];
  __shared__ float us[C];
  __shared__ float red[4];
  for (int c = tid; c < C; c += 256) mps[c] = mps_g[b * C + c];
  __syncthreads();
  for (int j = wid; j < CH; j += 4) {
    const float* wr = wqkv + (size_t)(h * CH + j) * C;
    float acc = 0.f;
    #pragma unroll
    for (int k = 0; k < 8; ++k) acc += wr[lane + k * 64] * mps[lane + k * 64];
    acc = wave_sum(acc);
    if (lane == 0) q0s[j] = acc + bqkv[h * CH + j];
  }
  __syncthreads();
  float a0 = 0.f, a1 = 0.f;
  #pragma unroll 4
  for (int j = 0; j < CH; ++j) {
    float qv = q0s[j];
    const float* wkr = wqkv + (size_t)(C + h * CH + j) * C;
    a0 += qv * wkr[tid];
    a1 += qv * wkr[tid + 256];
  }
  a0 *= 0.125f; a1 *= 0.125f;   // scale^2 = 1/sqrt(64)
  us[tid] = a0; us[tid + 256] = a1;
  u[(size_t)bh * C + tid] = a0;
  u[(size_t)bh * C + tid + 256] = a1;
  __syncthreads();
  float p = us[tid] * mps[tid] + us[tid + 256] * mps[tid + 256];
  p = wave_sum(p);
  if (lane == 0) red[wid] = p;
  __syncthreads();
  if (tid == 0) logit0[bh] = red[0] + red[1] + red[2] + red[3];
}

// ---- K3: logit partials. grid (8 lt, B, 4 cq) = 256 blocks, 512 thr.
// r-loop partially unrolled (4) to bound the load-hoisting window (anti-spill). ----
__global__ void __launch_bounds__(512, 2) k_logits(
    const float* __restrict__ x, const float* __restrict__ pos,
    const float* __restrict__ u_g, float* __restrict__ wpart) {
  __shared__ float us[NH][128];
  __shared__ float4 rlds[8][NH][64];   // 64 KB
  int lt = blockIdx.x, b = blockIdx.y, cq = blockIdx.z;
  int tid = threadIdx.x, w = tid >> 6, lane = tid & 63;
  for (int idx = tid; idx < NH * 128; idx += 512) {
    int h = idx >> 7, cc = idx & 127;
    us[h][cc] = u_g[(size_t)(b * NH + h) * C + cq * 128 + cc];
  }
  __syncthreads();
  float4 acc[NH];
  #pragma unroll
  for (int h = 0; h < NH; ++h) acc[h] = make_float4(0.f, 0.f, 0.f, 0.f);
  int c0 = cq * 128 + w * 16;
  int jb = lt * 256 + lane * 4;        // x column base for this lane
  const float4* x4 = reinterpret_cast<const float4*>(x)
                   + ((size_t)(b * C + c0)) * (D / 4) + (jb >> 2);
  const float* pb = pos + (size_t)c0 * L + jb + 1;
  #pragma unroll 4
  for (int r = 0; r < 16; ++r) {
    float4 v = x4[(size_t)r * (D / 4)];
    const float* pr = pb + (size_t)r * L;
    v.x += pr[0]; v.y += pr[1]; v.z += pr[2]; v.w += pr[3];
    #pragma unroll
    for (int h = 0; h < NH; ++h) {
      float uu = us[h][w * 16 + r];    // block-uniform broadcast
      acc[h].x += uu * v.x; acc[h].y += uu * v.y;
      acc[h].z += uu * v.z; acc[h].w += uu * v.w;
    }
  }
  #pragma unroll
  for (int h = 0; h < NH; ++h) rlds[w][h][lane] = acc[h];
  __syncthreads();
  int h = tid >> 6, slot = tid & 63;   // 512 threads <-> (h, slot)
  float4 s = rlds[0][h][slot];
  #pragma unroll
  for (int w2 = 1; w2 < 8; ++w2) {
    float4 t = rlds[w2][h][slot];
    s.x += t.x; s.y += t.y; s.z += t.z; s.w += t.w;
  }
  reinterpret_cast<float4*>(
      wpart + ((size_t)((b * NH + h) * NCQ + cq)) * (size_t)D + lt * 256)[slot] = s;
}

// ---- K4: softmax combine. One block per (b,h), 512 thr. Writes NORMALIZED
// weights e_g[bh][l] (sinv folded) and w0n[bh] = e0*sinv. ----
__global__ void __launch_bounds__(512) k_softmax(
    const float* __restrict__ wpart, const float* __restrict__ logit0,
    float* __restrict__ e_g, float* __restrict__ w0n) {
  int bh = blockIdx.x;
  int tid = threadIdx.x, wid = tid >> 6, lane = tid & 63;
  __shared__ float red[8];
  __shared__ float bc;
  const float* wp = wpart + (size_t)(bh * NCQ) * D;
  float s_arr[4];
  float m = -3.0e38f;
  #pragma unroll
  for (int k = 0; k < 4; ++k) {
    int l = k * 512 + tid;
    float s = wp[l] + wp[D + l] + wp[2 * D + l] + wp[3 * D + l];
    s_arr[k] = s;
    m = fmaxf(m, s);
  }
  float lg0 = logit0[bh];
  m = wave_max(m);
  if (lane == 0) red[wid] = m;
  __syncthreads();
  if (tid == 0) {
    float M = lg0;
    #pragma unroll
    for (int w = 0; w < 8; ++w) M = fmaxf(M, red[w]);
    bc = M;
  }
  __syncthreads();
  float M = bc;
  float e[4], ssum = 0.f;
  #pragma unroll
  for (int k = 0; k < 4; ++k) { e[k] = __expf(s_arr[k] - M); ssum += e[k]; }
  ssum = wave_sum(ssum);
  __syncthreads();
  if (lane == 0) red[wid] = ssum;
  __syncthreads();
  if (tid == 0) {
    float S = __expf(lg0 - M);
    #pragma unroll
    for (int w = 0; w < 8; ++w) S += red[w];
    bc = 1.0f / S;
  }
  __syncthreads();
  float sinv = bc;
  #pragma unroll
  for (int k = 0; k < 4; ++k)
    e_g[(size_t)bh * D + k * 512 + tid] = e[k] * sinv;
  if (tid == 0) w0n[bh] = __expf(lg0 - M) * sinv;
}

// ---- K5: xbar. grid (32 cc, B) = 256 blocks, 512 thr.
// e staged in LDS; k-loop partially unrolled (2) to bound the load-hoisting
// window (anti-spill: R11/R12's 62 MB scratch WRITE_SIZE). ----
__global__ void __launch_bounds__(512, 2) k_xbar(
    const float* __restrict__ x, const float* __restrict__ pos,
    const float* __restrict__ e_g, const float* __restrict__ w0n,
    const float* __restrict__ mps_g, float* __restrict__ xbar) {
  __shared__ float eL[NH][D];          // 64 KB
  int cc = blockIdx.x, b = blockIdx.y;
  int tid = threadIdx.x, w = tid >> 6, lane = tid & 63;
  {
    const float4* src = reinterpret_cast<const float4*>(e_g + (size_t)(b * NH) * D);
    float4* dst = reinterpret_cast<float4*>(&eL[0][0]);
    #pragma unroll
    for (int k = 0; k < 8; ++k) dst[k * 512 + tid] = src[k * 512 + tid];
  }
  __syncthreads();
  int c0 = cc * 16 + w * 2;            // wave owns 2 c-rows
  float accr[2][NH];
  #pragma unroll
  for (int r = 0; r < 2; ++r)
    #pragma unroll
    for (int h = 0; h < NH; ++h) accr[r][h] = 0.f;
  const float4* x4 = reinterpret_cast<const float4*>(x) + ((size_t)(b * C + c0)) * (D / 4);
  const float* pb = pos + (size_t)c0 * L + 1;   // pos[c0][l], l = j+1
  #pragma unroll 2
  for (int k = 0; k < 8; ++k) {
    int fi = k * 64 + lane;            // float4 index in row
    float4 e4[NH];
    #pragma unroll
    for (int h = 0; h < NH; ++h)
      e4[h] = reinterpret_cast<const float4*>(eL[h])[fi];
    #pragma unroll
    for (int r = 0; r < 2; ++r) {
      float4 xv = x4[(size_t)r * (D / 4) + fi];
      const float* pr = pb + (size_t)r * L + fi * 4;  // pos[c0+r][j+1..j+4]
      xv.x += pr[0]; xv.y += pr[1]; xv.z += pr[2]; xv.w += pr[3];
      #pragma unroll
      for (int h = 0; h < NH; ++h)
        accr[r][h] += e4[h].x * xv.x + e4[h].y * xv.y
                    + e4[h].z * xv.z + e4[h].w * xv.w;
    }
  }
  #pragma unroll
  for (int r = 0; r < 2; ++r) {
    int c = c0 + r;
    float mv = mps_g[b * C + c];
    #pragma unroll
    for (int h = 0; h < NH; ++h) {
      float t = wave_sum(accr[r][h]);
      if (lane == 0)
        xbar[(size_t)(b * NH + h) * C + c] = t + w0n[b * NH + h] * mv;
    }
  }
}

// ---- K6: a0[b, h*64+j] = W_v[o,:].xbar[b,h,:] + b_v[o]. Block = (b,h). ----
__global__ void __launch_bounds__(512) k_a0(
    const float* __restrict__ xbarg, const float* __restrict__ wqkv,
    const float* __restrict__ bqkv, float* __restrict__ a0v) {
  int bh = blockIdx.x, b = bh >> 3, h = bh & 7;
  int tid = threadIdx.x, wid = tid >> 6, lane = tid & 63;
  __shared__ float row[C];
  row[tid] = xbarg[(size_t)bh * C + tid];
  __syncthreads();
  float xr[8];
  #pragma unroll
  for (int k = 0; k < 8; ++k) xr[k] = row[k * 64 + lane];
  #pragma unroll 2
  for (int j = 0; j < 8; ++j) {
    int o = h * CH + wid * 8 + j;
    const float* wr = wqkv + (size_t)(2 * C + o) * C;
    float d = 0.f;
    #pragma unroll
    for (int k = 0; k < 8; ++k) d += wr[k * 64 + lane] * xr[k];
    d = wave_sum(d);
    if (lane == 0) a0v[b * C + o] = d + bqkv[2 * C + o];
  }
}

// ---- K7: out[b,o] = W_c[o,:].a0[b,:] + b_c[o]. Block = (b, 64-o chunk). ----
__global__ void __launch_bounds__(512) k_out(const float* __restrict__ wc,
                                             const float* __restrict__ bc,
                                             const float* __restrict__ a0v,
                                             float* __restrict__ out) {
  int bid = blockIdx.x, b = bid >> 3, og = (bid & 7) * 64;
  int tid = threadIdx.x, wid = tid >> 6, lane = tid & 63;
  __shared__ float row[C];
  row[tid] = a0v[b * C + tid];
  __syncthreads();
  float ar[8];
  #pragma unroll
  for (int k = 0; k < 8; ++k) ar[k] = row[k * 64 + lane];
  #pragma unroll 2
  for (int j = 0; j < 8; ++j) {
    int o = og + wid * 8 + j;
    const float* wr = wc + (size_t)o * C;
    float d = 0.f;
    #pragma unroll
    for (int k = 0; k < 8; ++k) d += wr[k * 64 + lane] * ar[k];
    d = wave_sum(d);
    if (lane == 0) out[b * C + o] = d + bc[o];
  }
}

extern "C" void kernel_launch(void* const* d_in, const int* in_sizes, int n_in,
                              void* d_out, int out_size, void* d_ws, size_t ws_size,
                              hipStream_t stream) {
  const float* x    = (const float*)d_in[0];
  const float* pos  = (const float*)d_in[1];
  const float* wqkv = (const float*)d_in[2];
  const float* bqkv = (const float*)d_in[3];
  const float* wc   = (const float*)d_in[4];
  const float* bc   = (const float*)d_in[5];
  float* out = (float*)d_out;
  float* ws  = (float*)d_ws;

  float* mps_g  = ws;               // 4096
  float* u      = ws + 4096;        // 32768
  float* logit0 = ws + 36864;       // 64
  float* a0v    = ws + 36928;       // 4096
  float* xbarg  = ws + 41024;       // 32768
  float* w0n    = ws + 73792;       // 64
  float* e_g    = ws + 73856;       // 64*2048 = 131072
  float* wpart  = ws + 204928;      // 64*4*2048 = 524288  (total ~2.9 MB)

  hipLaunchKernelGGL(k_mean,    dim3(B * C),     dim3(256), 0, stream, x, pos, mps_g);
  hipLaunchKernelGGL(k_qu,      dim3(B * NH),    dim3(256), 0, stream, wqkv, bqkv, mps_g, u, logit0);
  hipLaunchKernelGGL(k_logits,  dim3(8, B, NCQ), dim3(512), 0, stream, x, pos, u, wpart);
  hipLaunchKernelGGL(k_softmax, dim3(B * NH),    dim3(512), 0, stream, wpart, logit0, e_g, w0n);
  hipLaunchKernelGGL(k_xbar,    dim3(32, B),     dim3(512), 0, stream, x, pos, e_g, w0n, mps_g, xbarg);
  hipLaunchKernelGGL(k_a0,      dim3(B * NH),    dim3(512), 0, stream, xbarg, wqkv, bqkv, a0v);
  hipLaunchKernelGGL(k_out,     dim3(B * NH),    dim3(512), 0, stream, wc, bc, a0v, out);
}